// Round 5
// baseline (170.459 us; speedup 1.0000x reference)
//
#include <hip/hip_runtime.h>
#include <hip/hip_bf16.h>

// Sparse encoder layer: 3x submanifold conv (27-pt) + strided conv (8-pt),
// 4x training-mode BN+ReLU. bf16 MFMA (fp32 accum) for all convs.
//
// R3: split-K burst conv = 41 us; all pipes idle -> theory: L2 scattered-line
// service rate. R4: conv1 Cin=3 gather cut + BN fused into consumer gather.
// R4 BUG: missing neighbors (idx=-1) must contribute 0 AFTER BN; fused path
// applied BN to the zero-gathered row -> relu(shift) leaked. R5 fix: mask the
// A-fragment to zero post-BN-transform when nb<0.
//
// ws layout (bytes):
//   [0, 32768)        : stats partials, 4 stages x NCOPY(32) copies x 64 floats
//   [32768, +55296x3) : W1t/W2at/W2bt bf16 [27][32d][32c]
//   next 16384        : W3t bf16 [8][32][32]
//   then 3 x 8.4MB    : X, T, FB bf16 [N,32]

typedef __bf16 bf16_8 __attribute__((ext_vector_type(8)));
typedef float  f32x4  __attribute__((ext_vector_type(4)));

#define EPSV 1e-5f
#define NCOPY 32

__device__ inline bf16_8 bzero8() {
    bf16_8 z;
#pragma unroll
    for (int i = 0; i < 8; ++i) z[i] = (__bf16)0.f;
    return z;
}

__device__ inline bf16_8 gatherrow(const __bf16* __restrict__ src, int nb, int kh) {
    bf16_8 a = *(const bf16_8*)(src + (size_t)(nb < 0 ? 0 : nb) * 32 + kh * 8);
    if (nb < 0) a = bzero8();
    return a;
}

// Merged prep: feats fp32 [N,3] -> bf16 [N,32] padded; all W transposed+cast
// to [K][32d][32c]; stats partials zeroed.
__global__ void k_prep(const float* __restrict__ f,
                       const float* __restrict__ W1, const float* __restrict__ W2a,
                       const float* __restrict__ W2b, const float* __restrict__ W3,
                       __bf16* __restrict__ fb,
                       __bf16* __restrict__ w1t, __bf16* __restrict__ w2at,
                       __bf16* __restrict__ w2bt, __bf16* __restrict__ w3t,
                       float* __restrict__ statsAll, int n32) {
    int t = blockIdx.x * 256 + threadIdx.x;
    if (t < n32) {
        int s = t >> 5, c = t & 31;
        fb[t] = (c < 3) ? (__bf16)f[s * 3 + c] : (__bf16)0.f;
        return;
    }
    int u = t - n32;
    if (u < 27648) {
        int k = u >> 10, r = u & 1023, d = r >> 5, c = r & 31;
        w1t[u] = (c < 3) ? (__bf16)W1[(k * 3 + c) * 32 + d] : (__bf16)0.f;
    } else if (u < 2 * 27648) {
        int j = u - 27648;
        int k = j >> 10, r = j & 1023, d = r >> 5, c = r & 31;
        w2at[j] = (__bf16)W2a[(k * 32 + c) * 32 + d];
    } else if (u < 3 * 27648) {
        int j = u - 2 * 27648;
        int k = j >> 10, r = j & 1023, d = r >> 5, c = r & 31;
        w2bt[j] = (__bf16)W2b[(k * 32 + c) * 32 + d];
    } else if (u < 3 * 27648 + 8192) {
        int j = u - 3 * 27648;
        int k = j >> 10, r = j & 1023, d = r >> 5, c = r & 31;
        w3t[j] = (__bf16)W3[(k * 32 + c) * 32 + d];
    } else if (u < 3 * 27648 + 8192 + 4 * NCOPY * 64) {
        statsAll[u - 3 * 27648 - 8192] = 0.f;
    }
}

// Split-K gathered-GEMM conv. Block = 4 waves, 32 output sites.
// Wave w: offsets [w*KPW, ...), 2 groups of 16 sites. All idx then all gathers
// issued up-front; fp32 partials -> LDS -> reduce. Optional fused input-BN+ReLU
// (scale/shift finalized per-block from stats partials of the producing conv);
// missing neighbors are zeroed AFTER the BN transform (reference semantics).
// CIN3: only channels 0-7 are nonzero in src -> kh!=0 lanes skip the gather.
template <int KOFF, bool ADD, bool BNIN, bool CIN3>
__global__ __launch_bounds__(256, 4) void k_conv(
    const __bf16* __restrict__ src,       // [Nsrc,32] bf16 (raw, pre-BN)
    const int* __restrict__ idx,          // [nout,KOFF]
    const __bf16* __restrict__ Wt,        // [KOFF][32d][32c] bf16
    const __bf16* __restrict__ addsrc,    // [nout,32] bf16 or null (raw)
    __bf16* __restrict__ dst,             // [nout,32] bf16 (raw, pre-BN)
    const float* __restrict__ spart_in,   // producing conv's stats partials
    const float* __restrict__ gamma, const float* __restrict__ beta,
    float inv_cnt_in,
    float* __restrict__ spart_out,        // [NCOPY][64]
    int nout) {
    constexpr int KPW = (KOFF + 3) / 4;
    __shared__ float part[4][32][33];
    __shared__ float lst[64];
    __shared__ float sfin[64];
    __shared__ float lsc[32], lsh[32];

    const int tid = threadIdx.x;
    const int lane = tid & 63;
    const int wv = tid >> 6;
    const int base = blockIdx.x * 32;
    const int sl = lane & 15;   // A row / B col within 16
    const int kh = lane >> 4;   // k-quarter: channels kh*8..kh*8+7
    const int kbeg = wv * KPW;

    // ---- all idx loads (independent, issued first) ----
    int nb[2][KPW];
#pragma unroll
    for (int g = 0; g < 2; ++g) {
        const int s = base + g * 16 + sl;
        const bool v = (s < nout);
        const int* ip = idx + (size_t)(v ? s : 0) * KOFF;
#pragma unroll
        for (int j = 0; j < KPW; ++j) {
            const bool kv = (kbeg + j) < KOFF;
            int t = ip[kv ? (kbeg + j) : 0];
            nb[g][j] = (v && kv) ? t : -1;
        }
    }

    if (tid < 64) lst[tid] = 0.f;

    // ---- fused-BN prolog: finalize producing-stage stats (L2-hot 8KB) ----
    if (BNIN) {
        if (tid < 64) {
            float a = 0.f;
#pragma unroll
            for (int i = 0; i < NCOPY; ++i) a += spart_in[i * 64 + tid];
            sfin[tid] = a;
        }
        __syncthreads();
        if (tid < 32) {
            float mu = sfin[tid] * inv_cnt_in;
            float var = sfin[32 + tid] * inv_cnt_in - mu * mu;
            float s = gamma[tid] * rsqrtf(var + EPSV);
            lsc[tid] = s;
            lsh[tid] = beta[tid] - mu * s;
        }
        __syncthreads();
    }
    float scl[8], shf[8];
    if (BNIN) {
#pragma unroll
        for (int i = 0; i < 8; ++i) { scl[i] = lsc[kh * 8 + i]; shf[i] = lsh[kh * 8 + i]; }
    }

    // ---- all gathers (issued together) ----
    bf16_8 av[2][KPW];
#pragma unroll
    for (int j = 0; j < KPW; ++j)
#pragma unroll
        for (int g = 0; g < 2; ++g) {
            if (CIN3 && kh != 0)
                av[g][j] = bzero8();
            else
                av[g][j] = gatherrow(src, nb[g][j], kh);
        }

    // ---- MFMA chain (+ per-row BN transform when fused) ----
    f32x4 acc[2][2];
#pragma unroll
    for (int g = 0; g < 2; ++g)
#pragma unroll
        for (int h = 0; h < 2; ++h)
#pragma unroll
            for (int r = 0; r < 4; ++r) acc[g][h][r] = 0.f;

#pragma unroll
    for (int j = 0; j < KPW; ++j) {
        int kk = kbeg + j;
        if (kk > KOFF - 1) kk = KOFF - 1;  // av is zero there; value irrelevant
        bf16_8 b0 = *(const bf16_8*)(Wt + kk * 1024 + sl * 32 + kh * 8);
        bf16_8 b1 = *(const bf16_8*)(Wt + kk * 1024 + (16 + sl) * 32 + kh * 8);
        bf16_8 a0 = av[0][j], a1 = av[1][j];
        if (BNIN) {
#pragma unroll
            for (int i = 0; i < 8; ++i) {
                a0[i] = (__bf16)fmaxf(fmaf((float)a0[i], scl[i], shf[i]), 0.f);
                a1[i] = (__bf16)fmaxf(fmaf((float)a1[i], scl[i], shf[i]), 0.f);
            }
            // reference semantics: mask AFTER BN -> missing neighbor = 0
            if (nb[0][j] < 0) a0 = bzero8();
            if (nb[1][j] < 0) a1 = bzero8();
        }
        acc[0][0] = __builtin_amdgcn_mfma_f32_16x16x32_bf16(a0, b0, acc[0][0], 0, 0, 0);
        acc[0][1] = __builtin_amdgcn_mfma_f32_16x16x32_bf16(a0, b1, acc[0][1], 0, 0, 0);
        acc[1][0] = __builtin_amdgcn_mfma_f32_16x16x32_bf16(a1, b0, acc[1][0], 0, 0, 0);
        acc[1][1] = __builtin_amdgcn_mfma_f32_16x16x32_bf16(a1, b1, acc[1][1], 0, 0, 0);
    }

    // ---- partials to LDS ----
#pragma unroll
    for (int g = 0; g < 2; ++g)
#pragma unroll
        for (int h = 0; h < 2; ++h)
#pragma unroll
            for (int r = 0; r < 4; ++r)
                part[wv][g * 16 + kh * 4 + r][h * 16 + sl] = acc[g][h][r];
    __syncthreads();

    // ---- reduce + epilogue (threads 0..127: 32 sites x 4 ch-blocks) ----
    if (tid < 128) {
        const int sloc = tid >> 2;
        const int c0 = (tid & 3) * 8;
        float v[8];
#pragma unroll
        for (int i = 0; i < 8; ++i)
            v[i] = part[0][sloc][c0 + i] + part[1][sloc][c0 + i] +
                   part[2][sloc][c0 + i] + part[3][sloc][c0 + i];
        const int site = base + sloc;
        if (site < nout) {
            if (ADD) {
                bf16_8 ad = *(const bf16_8*)(addsrc + (size_t)site * 32 + c0);
#pragma unroll
                for (int i = 0; i < 8; ++i) v[i] += (float)ad[i];
            }
            bf16_8 o;
#pragma unroll
            for (int i = 0; i < 8; ++i) o[i] = (__bf16)v[i];
            *(bf16_8*)(dst + (size_t)site * 32 + c0) = o;
        } else {
#pragma unroll
            for (int i = 0; i < 8; ++i) v[i] = 0.f;
        }
        float sv[8], qv[8];
#pragma unroll
        for (int i = 0; i < 8; ++i) { sv[i] = v[i]; qv[i] = v[i] * v[i]; }
#pragma unroll
        for (int d = 4; d < 64; d <<= 1) {
#pragma unroll
            for (int i = 0; i < 8; ++i) {
                sv[i] += __shfl_xor(sv[i], d);
                qv[i] += __shfl_xor(qv[i], d);
            }
        }
        if ((lane & 60) == 0) {  // lanes 0..3 of waves 0,1
#pragma unroll
            for (int i = 0; i < 8; ++i) {
                atomicAdd(&lst[c0 + i], sv[i]);
                atomicAdd(&lst[32 + c0 + i], qv[i]);
            }
        }
    }
    __syncthreads();
    if (tid < 64)
        atomicAdd(&spart_out[(blockIdx.x & (NCOPY - 1)) * 64 + tid], lst[tid]);
}

// BN+ReLU apply -> fp32 output. Prolog: finalize stats from NCOPY partials.
__global__ __launch_bounds__(256) void k_bnout(
    const __bf16* __restrict__ src, const float* __restrict__ spart,
    const float* __restrict__ gamma, const float* __restrict__ beta,
    float inv_cnt, int nrows, float* __restrict__ dstf) {
    __shared__ float ss[64];
    __shared__ float sc[32], sh[32];
    const int tid = threadIdx.x;
    if (tid < 64) {
        float a = 0.f;
#pragma unroll
        for (int i = 0; i < NCOPY; ++i) a += spart[i * 64 + tid];
        ss[tid] = a;
    }
    __syncthreads();
    if (tid < 32) {
        float mu = ss[tid] * inv_cnt;
        float var = ss[32 + tid] * inv_cnt - mu * mu;
        float s = gamma[tid] * rsqrtf(var + EPSV);
        sc[tid] = s;
        sh[tid] = beta[tid] - mu * s;
    }
    __syncthreads();
    const int gtid = blockIdx.x * blockDim.x + tid;
    const int c0 = (gtid & 3) * 8;
    float scale[8], shift[8];
#pragma unroll
    for (int i = 0; i < 8; ++i) { scale[i] = sc[c0 + i]; shift[i] = sh[c0 + i]; }
    const int rstride = (gridDim.x * blockDim.x) >> 2;
    for (int r = gtid >> 2; r < nrows; r += rstride) {
        const int off = r * 32 + c0;
        bf16_8 v = *(const bf16_8*)(src + off);
        f32x4 lo, hi;
#pragma unroll
        for (int i = 0; i < 4; ++i) {
            lo[i] = fmaxf(fmaf((float)v[i], scale[i], shift[i]), 0.f);
            hi[i] = fmaxf(fmaf((float)v[4 + i], scale[4 + i], shift[4 + i]), 0.f);
        }
        *(f32x4*)(dstf + off) = lo;
        *(f32x4*)(dstf + off + 4) = hi;
    }
}

extern "C" void kernel_launch(void* const* d_in, const int* in_sizes, int n_in,
                              void* d_out, int out_size, void* d_ws, size_t ws_size,
                              hipStream_t stream) {
    const float* feats = (const float*)d_in[0];
    const int* nbr     = (const int*)d_in[1];
    const int* child   = (const int*)d_in[2];
    const float* W1  = (const float*)d_in[3];
    const float* W2a = (const float*)d_in[4];
    const float* W2b = (const float*)d_in[5];
    const float* W3  = (const float*)d_in[6];
    const float* g1 = (const float*)d_in[7];  const float* b1 = (const float*)d_in[8];
    const float* g2 = (const float*)d_in[9];  const float* b2 = (const float*)d_in[10];
    const float* g3 = (const float*)d_in[11]; const float* b3 = (const float*)d_in[12];
    const float* g4 = (const float*)d_in[13]; const float* b4 = (const float*)d_in[14];

    const int N = in_sizes[0] / 3;   // 131072
    const int M = in_sizes[2] / 8;   // output sites of strided conv

    float* outp = (float*)d_out;               // [M,32]
    float* ft2p = outp + (size_t)M * 32;       // [N,32]

    char* ws = (char*)d_ws;
    float* statsAll = (float*)ws;              // 4 stages x NCOPY x 64
    __bf16* w1t  = (__bf16*)(ws + 32768);
    __bf16* w2at = w1t + 27648;
    __bf16* w2bt = w2at + 27648;
    __bf16* w3t  = w2bt + 27648;
    __bf16* X  = (__bf16*)(ws + 32768 + 182272);
    __bf16* T  = X + (size_t)N * 32;
    __bf16* FB = T + (size_t)N * 32;

    float* s1 = statsAll;
    float* s2 = statsAll + NCOPY * 64;
    float* s3 = statsAll + 2 * NCOPY * 64;
    float* s4 = statsAll + 3 * NCOPY * 64;

    const int n32 = N * 32;
    const int ptot = n32 + 3 * 27648 + 8192 + 4 * NCOPY * 64;
    k_prep<<<(ptot + 255) / 256, 256, 0, stream>>>(feats, W1, W2a, W2b, W3,
                                                   FB, w1t, w2at, w2bt, w3t,
                                                   statsAll, n32);

    const int cgrid = (N + 31) / 32;
    const int cgrid3 = (M + 31) / 32;
    const float invN = 1.f / N, invM = 1.f / M;

    // x1 = conv1(featsb): Cin=3 -> only kh==0 lanes gather.   FB -> X, s1
    k_conv<27, false, false, true><<<cgrid, 256, 0, stream>>>(
        FB, nbr, w1t, nullptr, X, nullptr, nullptr, nullptr, 0.f, s1, N);
    // br1 = conv2a(bnrelu1(x1)) fused                         X -> T, s2
    k_conv<27, false, true, false><<<cgrid, 256, 0, stream>>>(
        X, nbr, w2at, nullptr, T, s1, g1, b1, invN, s2, N);
    // s = x1 + conv2b(bnrelu2(br1)) fused                     T (+X) -> FB, s3
    k_conv<27, true, true, false><<<cgrid, 256, 0, stream>>>(
        T, nbr, w2bt, X, FB, s2, g2, b2, invN, s3, N);
    // ft2 = bnrelu3(s) -> d_out (fp32)
    k_bnout<<<1024, 256, 0, stream>>>(FB, s3, g3, b3, invN, N, ft2p);
    // x3 = conv3(bnrelu3(s)) fused                            FB -> T, s4
    k_conv<8, false, true, false><<<cgrid3, 256, 0, stream>>>(
        FB, child, w3t, nullptr, T, s3, g3, b3, invN, s4, M);
    // out = bnrelu4(x3) -> d_out (fp32)
    k_bnout<<<1024, 256, 0, stream>>>(T, s4, g4, b4, invM, M, outp);
}